// Round 1
// baseline (175.077 us; speedup 1.0000x reference)
//
#include <hip/hip_runtime.h>

// BeBertEmbedding: out[b,s,d] = pe[s,d]
//                             + (input_ids[b,s]==0 ? W_tok[d,0]+b_tok[d] : 0)
//                             + (segment[b,s]==0   ? W_seg[d,0]+b_seg[d] : 0)
// The reference's where() keeps the gathered embedding ONLY for pad tokens
// (id==0), for which the gathered column is always column 0. Non-pad tokens
// get the constant float(padding_idx)=0.0 vector. So no vocab gather needed.
//
// R1 (prev session): one block per s; pe row + folded vectors in registers;
// loop over the 16 batch rows sharing that s. pe read exactly once (6 MB).
// R3 (this round): NT stores -> plain write-back stores. Timed-loop decomp
// shows embed at ~48us = 2.2 TB/s effective while the harness's own memset
// of the same buffers hits 6.6 TB/s. Theory: nontemporal stores bypass L2
// and stall on per-CU outstanding-write limits against HBM latency; plain
// stores are absorbed by L2 (34 TB/s) and written back asynchronously.
// L2 pollution is irrelevant (pe is read once into registers at block start).
// Also: precompute spread over 12 blocks x 64 so the 768 scattered 64B-line
// gathers of W_tok column 0 land on 12 CUs instead of 3.

#define VOCAB 32000
#define DMODEL 768
#define SEQ 2048
#define NB 16
#define D4 (DMODEL / 4)  // 192 float4 per row

typedef float f4 __attribute__((ext_vector_type(4)));

// Fold W[:,0] + b into contiguous vectors in workspace (ws is re-poisoned
// to 0xAA before every timed launch, so this must run every call — it's tiny).
__global__ __launch_bounds__(64) void precompute_vecs(
        const float* __restrict__ W_tok,
        const float* __restrict__ b_tok,
        const float* __restrict__ W_seg,
        const float* __restrict__ b_seg,
        float* __restrict__ v) {
    int d = blockIdx.x * 64 + threadIdx.x;
    if (d < DMODEL) {
        v[d]          = W_tok[(size_t)d * VOCAB] + b_tok[d];  // column 0 of W_tok
        v[DMODEL + d] = W_seg[d * 3] + b_seg[d];              // column 0 of W_seg
    }
}

// One block per s in [0,SEQ); 192 threads; each thread owns one float4 lane
// of the embedding row and stores it for all NB batches.
__global__ __launch_bounds__(192) void embed_kernel(
        const int* __restrict__ ids,    // [NB, SEQ]
        const int* __restrict__ segs,   // [NB, SEQ]
        const float* __restrict__ pe,   // [SEQ, DMODEL]
        const float* __restrict__ v,    // [2*DMODEL] precomputed
        float* __restrict__ out) {      // [NB, SEQ, DMODEL]
    const int s  = blockIdx.x;
    const int d4 = threadIdx.x;

    const f4 p  = ((const f4*)pe)[s * D4 + d4];
    const f4 vt = ((const f4*)v)[d4];
    const f4 vg = ((const f4*)(v + DMODEL))[d4];
    const f4 zero = {0.0f, 0.0f, 0.0f, 0.0f};

    // Preload all batch flags (wave-uniform loads, L2-resident).
    bool t[NB], g[NB];
#pragma unroll
    for (int b = 0; b < NB; ++b) {
        t[b] = (ids[b * SEQ + s] == 0);
        g[b] = (segs[b * SEQ + s] == 0);
    }

    f4* o4 = (f4*)out;
#pragma unroll
    for (int b = 0; b < NB; ++b) {
        // Match reference fp add order: (tok + pe) + seg
        f4 o = ((t[b] ? vt : zero) + p) + (g[b] ? vg : zero);
        o4[((size_t)b * SEQ + s) * D4 + d4] = o;  // plain write-back store
    }
}

extern "C" void kernel_launch(void* const* d_in, const int* in_sizes, int n_in,
                              void* d_out, int out_size, void* d_ws, size_t ws_size,
                              hipStream_t stream) {
    const int*   ids   = (const int*)d_in[0];
    const int*   segs  = (const int*)d_in[1];
    const float* W_tok = (const float*)d_in[2];
    const float* b_tok = (const float*)d_in[3];
    const float* W_seg = (const float*)d_in[4];
    const float* b_seg = (const float*)d_in[5];
    const float* pe    = (const float*)d_in[6];
    float* out = (float*)d_out;
    float* v   = (float*)d_ws;   // needs 2*768*4 = 6144 bytes

    precompute_vecs<<<12, 64, 0, stream>>>(W_tok, b_tok, W_seg, b_seg, v);
    embed_kernel<<<SEQ, 192, 0, stream>>>(ids, segs, pe, v, out);
}